// Round 5
// baseline (77.444 us; speedup 1.0000x reference)
//
#include <hip/hip_runtime.h>
#include <math.h>

#define C_CH 256
#define PRE 14
#define NPOOL 7
#define PIX (NPOOL * NPOOL)            // 49
#define OUT_PER_ROI (C_CH * PIX)       // 12544
#define HALF_C 128
#define HALF_OUT (HALF_C * PIX)        // 6272
#define SROW 132                       // sout: 128 + 4 pad

// level offsets in bf16 elements inside HWC workspace
#define OFF_P2 0
#define OFF_P3 16777216u
#define OFF_P4 20971520u
#define OFF_P5 22020096u
#define WS_ELEMS 22282240u             // bf16 elements; perm array lives after this

#define RB 528                         // transpose LDS row stride in bytes (512 + 16)
#define NTRANS 680                     // transpose blocks; block NTRANS = sorter

typedef float f4v __attribute__((ext_vector_type(4)));

static __device__ __forceinline__ unsigned short f2bf(float f) {
    unsigned int u = __float_as_uint(f);
    unsigned int r = (u + 0x7FFFu + ((u >> 16) & 1u)) >> 16;   // RNE
    return (unsigned short)r;
}
static __device__ __forceinline__ float bf2f(unsigned short b) {
    return __uint_as_float(((unsigned int)b) << 16);
}

// ---------------- fused transpose CHW fp32 -> HWC bf16 + ROI order sort ----------------
// Blocks 0..679: tile = 128 hw x 256 ch. Phase 1: 512B-contiguous NONTEMPORAL float4
// loads (read-once source must not evict ws from L2/L3), in-register 4x4 transpose,
// swizzled ds_write_b64. Phase 2: ds_read_b128 + 1KB-contiguous cached global stores.
// Block 680: bitonic-sorts ROI indices by (level, y, x) -> perm (L2 locality for roi_align).
__global__ __launch_bounds__(256) void transpose_all_k(
    const float* __restrict__ p2, const float* __restrict__ p3,
    const float* __restrict__ p4, const float* __restrict__ p5,
    unsigned short* __restrict__ ws, const float* __restrict__ rois,
    unsigned* __restrict__ perm, int N) {
    __shared__ unsigned char lds[128 * RB];    // 67584 B

    if (blockIdx.x == NTRANS) {
        // ---- ROI sort block ----
        unsigned long long* kv = (unsigned long long*)lds;  // 8 KB
        const int t = threadIdx.x;
        for (int i = t; i < 1024; i += 256) {
            unsigned key = 0xFFFFFFFFu;
            if (i < N) {
                const float x1 = rois[i * 5 + 1];
                const float y1 = rois[i * 5 + 2];
                const float x2 = rois[i * 5 + 3];
                const float y2 = rois[i * 5 + 4];
                float w = x2 - x1; w = (w <= 0.f) ? 1e-14f : w;
                float h = y2 - y1; h = (h <= 0.f) ? 1e-14f : h;
                float kf = 4.f + log2f(sqrtf(w * h) * (1.f / 224.f));
                kf = fminf(fmaxf(kf, 2.f), 5.f);
                const float kr = rintf(kf);
                const int lvl = (int)kr - 2;
                const float inv = exp2f(-kr);
                const int yi = (int)(y1 * inv);          // 0..255
                const int xi = (int)(x1 * inv);
                key = ((unsigned)lvl << 26) | ((unsigned)yi << 13) | (unsigned)xi;
            }
            kv[i] = ((unsigned long long)key << 32) | (unsigned)i;
        }
        __syncthreads();
        for (int k = 2; k <= 1024; k <<= 1) {
            for (int j = k >> 1; j > 0; j >>= 1) {
                for (int i = t; i < 512; i += 256) {
                    const int e = (i << 1) - (i & (j - 1));   // (e & j) == 0
                    const int f = e | j;
                    const bool up = ((e & k) == 0);
                    const unsigned long long A = kv[e], B = kv[f];
                    if ((A > B) == up) { kv[e] = B; kv[f] = A; }
                }
                __syncthreads();
            }
        }
        for (int i = t; i < N; i += 256) perm[i] = (unsigned)kv[i];
        return;
    }

    int b = blockIdx.x;
    const float* __restrict__ src;
    int HW2; unsigned int off;
    if (b < 512)      { src = p2; HW2 = 65536; off = OFF_P2; }
    else if (b < 640) { src = p3; HW2 = 16384; off = OFF_P3; b -= 512; }
    else if (b < 672) { src = p4; HW2 = 4096;  off = OFF_P4; b -= 640; }
    else              { src = p5; HW2 = 1024;  off = OFF_P5; b -= 672; }
    const int hw0 = b << 7;                    // 128 hw per block

    const int t   = threadIdx.x;
    const int hwq = t & 31;                    // hw quad 0..31 (covers 128 hw)
    const int cg  = t >> 5;                    // 0..7

    const int key = (hwq & 7) << 4;            // XOR swizzle key (bits 4..6)

    #pragma unroll
    for (int s = 0; s < 8; ++s) {
        const int c0 = (cg << 2) + (s << 5);   // channel base, 4 planes
        const float* g = src + (size_t)c0 * HW2 + hw0 + (hwq << 2);
        const f4v a0 = __builtin_nontemporal_load((const f4v*)(g));
        const f4v a1 = __builtin_nontemporal_load((const f4v*)(g + HW2));
        const f4v a2 = __builtin_nontemporal_load((const f4v*)(g + 2 * (size_t)HW2));
        const f4v a3 = __builtin_nontemporal_load((const f4v*)(g + 3 * (size_t)HW2));
        const int cb = (c0 << 1) ^ key;        // swizzled column byte
        unsigned char* base = &lds[(hwq << 2) * RB + cb];
        ushort4 w;
        w.x = f2bf(a0.x); w.y = f2bf(a1.x); w.z = f2bf(a2.x); w.w = f2bf(a3.x);
        *(ushort4*)(base) = w;
        w.x = f2bf(a0.y); w.y = f2bf(a1.y); w.z = f2bf(a2.y); w.w = f2bf(a3.y);
        *(ushort4*)(base + RB) = w;
        w.x = f2bf(a0.z); w.y = f2bf(a1.z); w.z = f2bf(a2.z); w.w = f2bf(a3.z);
        *(ushort4*)(base + 2 * RB) = w;
        w.x = f2bf(a0.w); w.y = f2bf(a1.w); w.z = f2bf(a2.w); w.w = f2bf(a3.w);
        *(ushort4*)(base + 3 * RB) = w;
    }
    __syncthreads();

    // Phase 2: each pass covers 8 rows x 512B; wave writes 1KB contiguous (cached).
    char* __restrict__ dstb = (char*)(ws + off + ((size_t)hw0 << 8));
    const int chunk = t & 31;
    const int hwl   = t >> 5;                  // 0..7
    #pragma unroll
    for (int p = 0; p < 16; ++p) {
        const int hw = (p << 3) + hwl;
        const int k2 = ((hw >> 2) & 7) << 4;
        const uint4 v = *(const uint4*)&lds[hw * RB + ((chunk << 4) ^ k2)];
        *(uint4*)(dstb + hw * 512 + (chunk << 4)) = v;
    }
}

// ---------------- main ROI-align + 2x2 maxpool (128 channels per block) ----------------
template <bool HWC>
__global__ __launch_bounds__(256, 6) void roi_align_k(
    const float* __restrict__ p2, const float* __restrict__ p3,
    const float* __restrict__ p4, const float* __restrict__ p5,
    const unsigned short* __restrict__ ws, const float* __restrict__ rois,
    const unsigned* __restrict__ perm, float* __restrict__ out) {

    __shared__ float sxw0[PRE], sxw1[PRE], syw0[PRE], syw1[PRE];
    __shared__ int   sxc0[PRE], sxc1[PRE], syc0[PRE], syc1[PRE];
    __shared__ float sout[PIX * SROW];          // 25872 B

    const int n   = HWC ? (int)perm[blockIdx.x] : (int)blockIdx.x;
    const int ch0 = blockIdx.y << 7;            // 0 or 128
    const float x1 = rois[n * 5 + 1];
    const float y1 = rois[n * 5 + 2];
    const float x2 = rois[n * 5 + 3];
    const float y2 = rois[n * 5 + 4];

    float w = x2 - x1; w = (w <= 0.f) ? 1e-14f : w;
    float h = y2 - y1; h = (h <= 0.f) ? 1e-14f : h;
    float kf = 4.f + log2f(sqrtf(w * h) * (1.f / 224.f));
    kf = fminf(fmaxf(kf, 2.f), 5.f);
    const float kr = rintf(kf);                 // round-half-even == jnp.round
    const int   lvl = (int)kr - 2;              // 0..3
    const float scale = exp2f(kr);
    const int   HW = 256 >> lvl;

    const int t = threadIdx.x;

    if (t < 2 * PRE) {
        const bool isx = t < PRE;
        const int  j = isx ? t : t - PRE;
        const float a1 = isx ? x1 : y1;
        const float a2 = isx ? x2 : y2;
        const float a1s = a1 / scale, a2s = a2 / scale;
        const float cen  = (a1s + a2s) * 0.5f;
        const float half = (a2s - a1s) * 0.5f;
        const float tt = -1.f + (2.f / 13.f) * (float)j;
        const float p  = cen + tt * half;
        const float p0 = floorf(p);
        const float d  = p - p0;
        const float HWf = (float)HW;
        const float m0 = (p0 >= 0.f && p0 < HWf) ? 1.f : 0.f;
        const float m1 = (p0 + 1.f >= 0.f && p0 + 1.f < HWf) ? 1.f : 0.f;
        const int c0i = min(max((int)p0, 0), HW - 1);
        const int c1i = min(max((int)p0 + 1, 0), HW - 1);
        if (isx) { sxw0[j] = (1.f - d) * m0; sxw1[j] = d * m1; sxc0[j] = c0i; sxc1[j] = c1i; }
        else     { syw0[j] = (1.f - d) * m0; syw1[j] = d * m1; syc0[j] = c0i; syc1[j] = c1i; }
    }
    __syncthreads();

    const int g     = t & 31;                   // channel group within half: 32 x 4ch = 128
    const int ph    = t >> 5;                   // 0..7 pixel phase
    const int cbase = ch0 + (g << 2);

    const unsigned short* __restrict__ fb = nullptr;
    const float* __restrict__ fbF = nullptr;
    if (HWC) {
        const unsigned int off = (lvl == 0) ? OFF_P2 : (lvl == 1) ? OFF_P3 : (lvl == 2) ? OFF_P4 : OFF_P5;
        fb = ws + off + cbase;
    } else {
        fbF = (lvl == 0) ? p2 : (lvl == 1) ? p3 : (lvl == 2) ? p4 : p5;
    }
    const int HW2 = HW * HW;

    for (int p = ph; p < PIX; p += 8) {
        const int oy = p / 7;
        const int ox = p - oy * 7;
        float4 m = make_float4(-3.4e38f, -3.4e38f, -3.4e38f, -3.4e38f);
        #pragma unroll
        for (int sy = 0; sy < 2; ++sy) {
            const int i = oy * 2 + sy;
            const float wy0 = syw0[i], wy1 = syw1[i];
            const int   yc0 = syc0[i], yc1 = syc1[i];
            #pragma unroll
            for (int sx = 0; sx < 2; ++sx) {
                const int j = ox * 2 + sx;
                const float wx0 = sxw0[j], wx1 = sxw1[j];
                const int   xc0 = sxc0[j], xc1 = sxc1[j];
                const float w00 = wy0 * wx0, w01 = wy0 * wx1;
                const float w10 = wy1 * wx0, w11 = wy1 * wx1;
                float4 v;
                if (HWC) {
                    const ushort4 a00 = *(const ushort4*)(fb + ((yc0 * HW + xc0) << 8));
                    const ushort4 a01 = *(const ushort4*)(fb + ((yc0 * HW + xc1) << 8));
                    const ushort4 a10 = *(const ushort4*)(fb + ((yc1 * HW + xc0) << 8));
                    const ushort4 a11 = *(const ushort4*)(fb + ((yc1 * HW + xc1) << 8));
                    v.x = fmaf(bf2f(a00.x), w00, fmaf(bf2f(a01.x), w01, fmaf(bf2f(a10.x), w10, bf2f(a11.x) * w11)));
                    v.y = fmaf(bf2f(a00.y), w00, fmaf(bf2f(a01.y), w01, fmaf(bf2f(a10.y), w10, bf2f(a11.y) * w11)));
                    v.z = fmaf(bf2f(a00.z), w00, fmaf(bf2f(a01.z), w01, fmaf(bf2f(a10.z), w10, bf2f(a11.z) * w11)));
                    v.w = fmaf(bf2f(a00.w), w00, fmaf(bf2f(a01.w), w01, fmaf(bf2f(a10.w), w10, bf2f(a11.w) * w11)));
                } else {
                    float vv[4];
                    #pragma unroll
                    for (int k = 0; k < 4; ++k) {
                        const size_t cb = (size_t)(cbase + k) * HW2;
                        const float a00 = fbF[cb + yc0 * HW + xc0];
                        const float a01 = fbF[cb + yc0 * HW + xc1];
                        const float a10 = fbF[cb + yc1 * HW + xc0];
                        const float a11 = fbF[cb + yc1 * HW + xc1];
                        vv[k] = fmaf(a00, w00, fmaf(a01, w01, fmaf(a10, w10, a11 * w11)));
                    }
                    v.x = vv[0]; v.y = vv[1]; v.z = vv[2]; v.w = vv[3];
                }
                m.x = fmaxf(m.x, v.x);
                m.y = fmaxf(m.y, v.y);
                m.z = fmaxf(m.z, v.z);
                m.w = fmaxf(m.w, v.w);
            }
        }
        *(float4*)&sout[p * SROW + (g << 2)] = m;
    }
    __syncthreads();

    // coalesced NCHW write of this channel-half — nontemporal (out is never re-read;
    // keep it out of L2/L3 so ws stays resident)
    const size_t ob = (size_t)n * OUT_PER_ROI + (size_t)ch0 * PIX;
    for (int o = t; o < HALF_OUT; o += 256) {
        const int c  = o / PIX;
        const int pp = o - c * PIX;
        __builtin_nontemporal_store(sout[pp * SROW + c], &out[ob + o]);
    }
}

extern "C" void kernel_launch(void* const* d_in, const int* in_sizes, int n_in,
                              void* d_out, int out_size, void* d_ws, size_t ws_size,
                              hipStream_t stream) {
    const float* p2   = (const float*)d_in[0];
    const float* p3   = (const float*)d_in[1];
    const float* p4   = (const float*)d_in[2];
    const float* p5   = (const float*)d_in[3];
    const float* rois = (const float*)d_in[4];
    float* out = (float*)d_out;
    const int N = in_sizes[4] / 5;

    const size_t need = (size_t)WS_ELEMS * sizeof(unsigned short) + 4096;
    if (ws_size >= need && N <= 1024) {
        unsigned short* ws = (unsigned short*)d_ws;
        unsigned* perm = (unsigned*)((char*)d_ws + (size_t)WS_ELEMS * sizeof(unsigned short));
        transpose_all_k<<<NTRANS + 1, 256, 0, stream>>>(p2, p3, p4, p5, ws, rois, perm, N);
        roi_align_k<true><<<dim3(N, 2), 256, 0, stream>>>(p2, p3, p4, p5, ws, rois, perm, out);
    } else {
        roi_align_k<false><<<dim3(N, 2), 256, 0, stream>>>(p2, p3, p4, p5, nullptr, rois, nullptr, out);
    }
}

// Round 7
// 55.916 us; speedup vs baseline: 1.3850x; 1.3850x over previous
//
#include <hip/hip_runtime.h>
#include <math.h>

#define C_CH 256
#define PRE 14
#define NPOOL 7
#define PIX (NPOOL * NPOOL)            // 49
#define OUT_PER_ROI (C_CH * PIX)       // 12544
#define HALF_OUT (128 * PIX)           // 6272
#define SROW 132                       // sout row stride: 128 channels + 4 pad (pixel-major)

// level offsets in bf16 elements inside HWC workspace
#define OFF_P2 0
#define OFF_P3 16777216u
#define OFF_P4 20971520u
#define OFF_P5 22020096u
#define WS_ELEMS 22282240u

#define RB 528                         // transpose LDS row stride in bytes (512 + 16)

static __device__ __forceinline__ unsigned short f2bf(float f) {
    unsigned int u = __float_as_uint(f);
    unsigned int r = (u + 0x7FFFu + ((u >> 16) & 1u)) >> 16;   // RNE
    return (unsigned short)r;
}
static __device__ __forceinline__ float bfLO(unsigned int u) {   // low bf16 of dword
    return __uint_as_float(u << 16);
}
static __device__ __forceinline__ float bfHI(unsigned int u) {   // high bf16 of dword
    return __uint_as_float(u & 0xFFFF0000u);
}

// 4-channel bilinear from 4 corner uint2 (4 bf16 ch each) and corner weights w
static __device__ __forceinline__ float4 bilerp4(uint2 a00, uint2 a01, uint2 a10, uint2 a11, float4 w) {
    float4 r;
    r.x = fmaf(bfLO(a00.x), w.x, fmaf(bfLO(a01.x), w.y, fmaf(bfLO(a10.x), w.z, bfLO(a11.x) * w.w)));
    r.y = fmaf(bfHI(a00.x), w.x, fmaf(bfHI(a01.x), w.y, fmaf(bfHI(a10.x), w.z, bfHI(a11.x) * w.w)));
    r.z = fmaf(bfLO(a00.y), w.x, fmaf(bfLO(a01.y), w.y, fmaf(bfLO(a10.y), w.z, bfLO(a11.y) * w.w)));
    r.w = fmaf(bfHI(a00.y), w.x, fmaf(bfHI(a01.y), w.y, fmaf(bfHI(a10.y), w.z, bfHI(a11.y) * w.w)));
    return r;
}

// ---------------- fused transpose CHW fp32 -> HWC bf16 (all 4 levels) ----------------
// (R4 version: cached loads/stores; 128hw x 256ch tile; 512B-contiguous reads,
//  in-register 4x4 transpose, swizzled LDS, 1KB-contiguous writes)
__global__ __launch_bounds__(256) void transpose_all_k(
    const float* __restrict__ p2, const float* __restrict__ p3,
    const float* __restrict__ p4, const float* __restrict__ p5,
    unsigned short* __restrict__ ws) {
    __shared__ unsigned char lds[128 * RB];    // 67584 B

    int b = blockIdx.x;
    const float* __restrict__ src;
    int HW2; unsigned int off;
    if (b < 512)      { src = p2; HW2 = 65536; off = OFF_P2; }
    else if (b < 640) { src = p3; HW2 = 16384; off = OFF_P3; b -= 512; }
    else if (b < 672) { src = p4; HW2 = 4096;  off = OFF_P4; b -= 640; }
    else              { src = p5; HW2 = 1024;  off = OFF_P5; b -= 672; }
    const int hw0 = b << 7;

    const int t   = threadIdx.x;
    const int hwq = t & 31;
    const int cg  = t >> 5;
    const int key = (hwq & 7) << 4;

    #pragma unroll
    for (int s = 0; s < 8; ++s) {
        const int c0 = (cg << 2) + (s << 5);
        const float* g = src + (size_t)c0 * HW2 + hw0 + (hwq << 2);
        const float4 a0 = *(const float4*)(g);
        const float4 a1 = *(const float4*)(g + HW2);
        const float4 a2 = *(const float4*)(g + 2 * (size_t)HW2);
        const float4 a3 = *(const float4*)(g + 3 * (size_t)HW2);
        const int cb = (c0 << 1) ^ key;
        unsigned char* base = &lds[(hwq << 2) * RB + cb];
        ushort4 w;
        w.x = f2bf(a0.x); w.y = f2bf(a1.x); w.z = f2bf(a2.x); w.w = f2bf(a3.x);
        *(ushort4*)(base) = w;
        w.x = f2bf(a0.y); w.y = f2bf(a1.y); w.z = f2bf(a2.y); w.w = f2bf(a3.y);
        *(ushort4*)(base + RB) = w;
        w.x = f2bf(a0.z); w.y = f2bf(a1.z); w.z = f2bf(a2.z); w.w = f2bf(a3.z);
        *(ushort4*)(base + 2 * RB) = w;
        w.x = f2bf(a0.w); w.y = f2bf(a1.w); w.z = f2bf(a2.w); w.w = f2bf(a3.w);
        *(ushort4*)(base + 3 * RB) = w;
    }
    __syncthreads();

    char* __restrict__ dstb = (char*)(ws + off + ((size_t)hw0 << 8));
    const int chunk = t & 31;
    const int hwl   = t >> 5;
    #pragma unroll
    for (int p = 0; p < 16; ++p) {
        const int hw = (p << 3) + hwl;
        const int k2 = ((hw >> 2) & 7) << 4;
        const uint4 v = *(const uint4*)&lds[hw * RB + ((chunk << 4) ^ k2)];
        *(uint4*)(dstb + hw * 512 + (chunk << 4)) = v;
    }
}

// ---------------- main ROI-align + 2x2 maxpool (128 channels per block) ----------------
template <bool HWC>
__global__ __launch_bounds__(256, 6) void roi_align_k(
    const float* __restrict__ p2, const float* __restrict__ p3,
    const float* __restrict__ p4, const float* __restrict__ p5,
    const unsigned short* __restrict__ ws, const float* __restrict__ rois,
    float* __restrict__ out) {

    __shared__ float sxw0[PRE], sxw1[PRE], syw0[PRE], syw1[PRE];
    __shared__ int   sxc0[PRE], sxc1[PRE], syc0[PRE], syc1[PRE];
    __shared__ float4 wtab[PRE * PRE];          // 3136 B: per-sample corner weights
    __shared__ int4   otab[PRE * PRE];          // 3136 B: per-sample corner byte offsets
    __shared__ float  sout[PIX * SROW];         // 25872 B (pixel-major: [pixel][channel])

    const int n   = blockIdx.x;
    const int ch0 = blockIdx.y << 7;            // 0 or 128
    const float x1 = rois[n * 5 + 1];
    const float y1 = rois[n * 5 + 2];
    const float x2 = rois[n * 5 + 3];
    const float y2 = rois[n * 5 + 4];

    float w = x2 - x1; w = (w <= 0.f) ? 1e-14f : w;
    float h = y2 - y1; h = (h <= 0.f) ? 1e-14f : h;
    float kf = 4.f + log2f(sqrtf(w * h) * (1.f / 224.f));
    kf = fminf(fmaxf(kf, 2.f), 5.f);
    const float kr = rintf(kf);                 // round-half-even == jnp.round
    const int   lvl = (int)kr - 2;              // 0..3
    const float scale = exp2f(kr);
    const int   HW = 256 >> lvl;

    const int t = threadIdx.x;

    if (t < 2 * PRE) {
        const bool isx = t < PRE;
        const int  j = isx ? t : t - PRE;
        const float a1 = isx ? x1 : y1;
        const float a2 = isx ? x2 : y2;
        const float a1s = a1 / scale, a2s = a2 / scale;
        const float cen  = (a1s + a2s) * 0.5f;
        const float half = (a2s - a1s) * 0.5f;
        const float tt = -1.f + (2.f / 13.f) * (float)j;
        const float p  = cen + tt * half;
        const float p0 = floorf(p);
        const float d  = p - p0;
        const float HWf = (float)HW;
        const float m0 = (p0 >= 0.f && p0 < HWf) ? 1.f : 0.f;
        const float m1 = (p0 + 1.f >= 0.f && p0 + 1.f < HWf) ? 1.f : 0.f;
        const int c0i = min(max((int)p0, 0), HW - 1);
        const int c1i = min(max((int)p0 + 1, 0), HW - 1);
        if (isx) { sxw0[j] = (1.f - d) * m0; sxw1[j] = d * m1; sxc0[j] = c0i; sxc1[j] = c1i; }
        else     { syw0[j] = (1.f - d) * m0; syw1[j] = d * m1; syc0[j] = c0i; syc1[j] = c1i; }
    }
    __syncthreads();

    if (HWC) {
        // build per-sample tables: s = i*14 + j  (i = y sample row, j = x sample col)
        for (int s = t; s < PRE * PRE; s += 256) {
            const int i = s / PRE;
            const int j = s - i * PRE;
            wtab[s] = make_float4(syw0[i] * sxw0[j], syw0[i] * sxw1[j],
                                  syw1[i] * sxw0[j], syw1[i] * sxw1[j]);
            otab[s] = make_int4((syc0[i] * HW + sxc0[j]) << 9, (syc0[i] * HW + sxc1[j]) << 9,
                                (syc1[i] * HW + sxc0[j]) << 9, (syc1[i] * HW + sxc1[j]) << 9);
        }
        __syncthreads();
    }

    const int g     = t & 31;                   // channel group within half (32 x 4ch)
    const int ph    = t >> 5;                   // 0..7 pixel phase
    const int cbase = ch0 + (g << 2);

    if (HWC) {
        const unsigned int off = (lvl == 0) ? OFF_P2 : (lvl == 1) ? OFF_P3 : (lvl == 2) ? OFF_P4 : OFF_P5;
        const char* __restrict__ base = (const char*)(ws + off);
        const int cb2 = cbase << 1;             // channel byte offset within 512B texel row

        for (int p = ph; p < PIX; p += 8) {
            const int oy = p / 7;
            const int ox = p - oy * 7;
            const int s00 = oy * 28 + (ox << 1);   // (2oy)*14 + 2ox

            // samples A=(0,0) B=(0,1) C=(1,0) D=(1,1) of the 2x2 pool window
            const int4  oA = otab[s00];      const float4 wA = wtab[s00];
            const int4  oB = otab[s00 + 1];  const float4 wB = wtab[s00 + 1];
            const uint2 A00 = *(const uint2*)(base + (oA.x + cb2));
            const uint2 A01 = *(const uint2*)(base + (oA.y + cb2));
            const uint2 A10 = *(const uint2*)(base + (oA.z + cb2));
            const uint2 A11 = *(const uint2*)(base + (oA.w + cb2));
            const uint2 B00 = *(const uint2*)(base + (oB.x + cb2));
            const uint2 B01 = *(const uint2*)(base + (oB.y + cb2));
            const uint2 B10 = *(const uint2*)(base + (oB.z + cb2));
            const uint2 B11 = *(const uint2*)(base + (oB.w + cb2));
            const float4 vA = bilerp4(A00, A01, A10, A11, wA);
            const float4 vB = bilerp4(B00, B01, B10, B11, wB);

            const int4  oC = otab[s00 + 14]; const float4 wC = wtab[s00 + 14];
            const int4  oD = otab[s00 + 15]; const float4 wD = wtab[s00 + 15];
            const uint2 C00 = *(const uint2*)(base + (oC.x + cb2));
            const uint2 C01 = *(const uint2*)(base + (oC.y + cb2));
            const uint2 C10 = *(const uint2*)(base + (oC.z + cb2));
            const uint2 C11 = *(const uint2*)(base + (oC.w + cb2));
            const uint2 D00 = *(const uint2*)(base + (oD.x + cb2));
            const uint2 D01 = *(const uint2*)(base + (oD.y + cb2));
            const uint2 D10 = *(const uint2*)(base + (oD.z + cb2));
            const uint2 D11 = *(const uint2*)(base + (oD.w + cb2));
            const float4 vC = bilerp4(C00, C01, C10, C11, wC);
            const float4 vD = bilerp4(D00, D01, D10, D11, wD);

            float4 m;
            m.x = fmaxf(fmaxf(vA.x, vB.x), fmaxf(vC.x, vD.x));
            m.y = fmaxf(fmaxf(vA.y, vB.y), fmaxf(vC.y, vD.y));
            m.z = fmaxf(fmaxf(vA.z, vB.z), fmaxf(vC.z, vD.z));
            m.w = fmaxf(fmaxf(vA.w, vB.w), fmaxf(vC.w, vD.w));
            *(float4*)&sout[p * SROW + (g << 2)] = m;
        }
    } else {
        const float* __restrict__ fbF = (lvl == 0) ? p2 : (lvl == 1) ? p3 : (lvl == 2) ? p4 : p5;
        const int HW2 = HW * HW;
        for (int p = ph; p < PIX; p += 8) {
            const int oy = p / 7;
            const int ox = p - oy * 7;
            float4 m = make_float4(-3.4e38f, -3.4e38f, -3.4e38f, -3.4e38f);
            #pragma unroll
            for (int sy = 0; sy < 2; ++sy) {
                const int i = oy * 2 + sy;
                const float wy0 = syw0[i], wy1 = syw1[i];
                const int   yc0 = syc0[i], yc1 = syc1[i];
                #pragma unroll
                for (int sx = 0; sx < 2; ++sx) {
                    const int j = ox * 2 + sx;
                    const float w00 = wy0 * sxw0[j], w01 = wy0 * sxw1[j];
                    const float w10 = wy1 * sxw0[j], w11 = wy1 * sxw1[j];
                    const int   xc0 = sxc0[j], xc1 = sxc1[j];
                    float vv[4];
                    #pragma unroll
                    for (int k = 0; k < 4; ++k) {
                        const size_t cb = (size_t)(cbase + k) * HW2;
                        const float a00 = fbF[cb + yc0 * HW + xc0];
                        const float a01 = fbF[cb + yc0 * HW + xc1];
                        const float a10 = fbF[cb + yc1 * HW + xc0];
                        const float a11 = fbF[cb + yc1 * HW + xc1];
                        vv[k] = fmaf(a00, w00, fmaf(a01, w01, fmaf(a10, w10, a11 * w11)));
                    }
                    m.x = fmaxf(m.x, vv[0]);
                    m.y = fmaxf(m.y, vv[1]);
                    m.z = fmaxf(m.z, vv[2]);
                    m.w = fmaxf(m.w, vv[3]);
                }
            }
            *(float4*)&sout[p * SROW + (g << 2)] = m;
        }
    }
    __syncthreads();

    // coalesced NCHW write of this channel-half (cached stores)
    const size_t ob = (size_t)n * OUT_PER_ROI + (size_t)ch0 * PIX;
    for (int o = t; o < HALF_OUT; o += 256) {
        const int c  = o / PIX;
        const int pp = o - c * PIX;
        out[ob + o] = sout[pp * SROW + c];
    }
}

extern "C" void kernel_launch(void* const* d_in, const int* in_sizes, int n_in,
                              void* d_out, int out_size, void* d_ws, size_t ws_size,
                              hipStream_t stream) {
    const float* p2   = (const float*)d_in[0];
    const float* p3   = (const float*)d_in[1];
    const float* p4   = (const float*)d_in[2];
    const float* p5   = (const float*)d_in[3];
    const float* rois = (const float*)d_in[4];
    float* out = (float*)d_out;
    const int N = in_sizes[4] / 5;

    const size_t need = (size_t)WS_ELEMS * sizeof(unsigned short);
    if (ws_size >= need) {
        unsigned short* ws = (unsigned short*)d_ws;
        transpose_all_k<<<680, 256, 0, stream>>>(p2, p3, p4, p5, ws);
        roi_align_k<true><<<dim3(N, 2), 256, 0, stream>>>(p2, p3, p4, p5, ws, rois, out);
    } else {
        roi_align_k<false><<<dim3(N, 2), 256, 0, stream>>>(p2, p3, p4, p5, nullptr, rois, out);
    }
}

// Round 8
// 55.511 us; speedup vs baseline: 1.3951x; 1.0073x over previous
//
#include <hip/hip_runtime.h>
#include <math.h>

#define C_CH 256
#define PRE 14
#define NPOOL 7
#define PIX (NPOOL * NPOOL)            // 49
#define OUT_PER_ROI (C_CH * PIX)       // 12544
#define QTR_OUT (64 * PIX)             // 3136
#define SROW 68                        // sout row stride: 64 channels + 4 pad (pixel-major)

// level offsets in bf16 elements inside HWC workspace
#define OFF_P2 0
#define OFF_P3 16777216u
#define OFF_P4 20971520u
#define OFF_P5 22020096u
#define WS_ELEMS 22282240u

#define RB 528                         // transpose LDS row stride in bytes (512 + 16)

static __device__ __forceinline__ unsigned short f2bf(float f) {
    unsigned int u = __float_as_uint(f);
    unsigned int r = (u + 0x7FFFu + ((u >> 16) & 1u)) >> 16;   // RNE
    return (unsigned short)r;
}
static __device__ __forceinline__ float bfLO(unsigned int u) { return __uint_as_float(u << 16); }
static __device__ __forceinline__ float bfHI(unsigned int u) { return __uint_as_float(u & 0xFFFF0000u); }

static __device__ __forceinline__ float4 bilerp4(uint2 a00, uint2 a01, uint2 a10, uint2 a11, float4 w) {
    float4 r;
    r.x = fmaf(bfLO(a00.x), w.x, fmaf(bfLO(a01.x), w.y, fmaf(bfLO(a10.x), w.z, bfLO(a11.x) * w.w)));
    r.y = fmaf(bfHI(a00.x), w.x, fmaf(bfHI(a01.x), w.y, fmaf(bfHI(a10.x), w.z, bfHI(a11.x) * w.w)));
    r.z = fmaf(bfLO(a00.y), w.x, fmaf(bfLO(a01.y), w.y, fmaf(bfLO(a10.y), w.z, bfLO(a11.y) * w.w)));
    r.w = fmaf(bfHI(a00.y), w.x, fmaf(bfHI(a01.y), w.y, fmaf(bfHI(a10.y), w.z, bfHI(a11.y) * w.w)));
    return r;
}

// ---------------- fused transpose CHW fp32 -> HWC bf16 (all 4 levels) ----------------
// (R4 version: cached loads/stores; 128hw x 256ch tile; 512B-contiguous reads,
//  in-register 4x4 transpose, swizzled LDS, 1KB-contiguous writes)
__global__ __launch_bounds__(256) void transpose_all_k(
    const float* __restrict__ p2, const float* __restrict__ p3,
    const float* __restrict__ p4, const float* __restrict__ p5,
    unsigned short* __restrict__ ws) {
    __shared__ unsigned char lds[128 * RB];    // 67584 B

    int b = blockIdx.x;
    const float* __restrict__ src;
    int HW2; unsigned int off;
    if (b < 512)      { src = p2; HW2 = 65536; off = OFF_P2; }
    else if (b < 640) { src = p3; HW2 = 16384; off = OFF_P3; b -= 512; }
    else if (b < 672) { src = p4; HW2 = 4096;  off = OFF_P4; b -= 640; }
    else              { src = p5; HW2 = 1024;  off = OFF_P5; b -= 672; }
    const int hw0 = b << 7;

    const int t   = threadIdx.x;
    const int hwq = t & 31;
    const int cg  = t >> 5;
    const int key = (hwq & 7) << 4;

    #pragma unroll
    for (int s = 0; s < 8; ++s) {
        const int c0 = (cg << 2) + (s << 5);
        const float* g = src + (size_t)c0 * HW2 + hw0 + (hwq << 2);
        const float4 a0 = *(const float4*)(g);
        const float4 a1 = *(const float4*)(g + HW2);
        const float4 a2 = *(const float4*)(g + 2 * (size_t)HW2);
        const float4 a3 = *(const float4*)(g + 3 * (size_t)HW2);
        const int cb = (c0 << 1) ^ key;
        unsigned char* base = &lds[(hwq << 2) * RB + cb];
        ushort4 w;
        w.x = f2bf(a0.x); w.y = f2bf(a1.x); w.z = f2bf(a2.x); w.w = f2bf(a3.x);
        *(ushort4*)(base) = w;
        w.x = f2bf(a0.y); w.y = f2bf(a1.y); w.z = f2bf(a2.y); w.w = f2bf(a3.y);
        *(ushort4*)(base + RB) = w;
        w.x = f2bf(a0.z); w.y = f2bf(a1.z); w.z = f2bf(a2.z); w.w = f2bf(a3.z);
        *(ushort4*)(base + 2 * RB) = w;
        w.x = f2bf(a0.w); w.y = f2bf(a1.w); w.z = f2bf(a2.w); w.w = f2bf(a3.w);
        *(ushort4*)(base + 3 * RB) = w;
    }
    __syncthreads();

    char* __restrict__ dstb = (char*)(ws + off + ((size_t)hw0 << 8));
    const int chunk = t & 31;
    const int hwl   = t >> 5;
    #pragma unroll
    for (int p = 0; p < 16; ++p) {
        const int hw = (p << 3) + hwl;
        const int k2 = ((hw >> 2) & 7) << 4;
        const uint4 v = *(const uint4*)&lds[hw * RB + ((chunk << 4) ^ k2)];
        *(uint4*)(dstb + hw * 512 + (chunk << 4)) = v;
    }
}

// ---------------- main ROI-align + 2x2 maxpool (64 channels per block) ----------------
template <bool HWC>
__global__ __launch_bounds__(256, 6) void roi_align_k(
    const float* __restrict__ p2, const float* __restrict__ p3,
    const float* __restrict__ p4, const float* __restrict__ p5,
    const unsigned short* __restrict__ ws, const float* __restrict__ rois,
    float* __restrict__ out) {

    __shared__ float sxw0[PRE], sxw1[PRE], syw0[PRE], syw1[PRE];
    __shared__ int   sxc0[PRE], sxc1[PRE], syc0[PRE], syc1[PRE];
    __shared__ float4 wtab[PRE * PRE];          // 3136 B
    __shared__ int4   otab[PRE * PRE];          // 3136 B
    __shared__ float  sout[PIX * SROW];         // 13328 B (pixel-major: [pixel][channel])

    const int n   = blockIdx.x;
    const int ch0 = blockIdx.y << 6;            // 0,64,128,192
    const float x1 = rois[n * 5 + 1];
    const float y1 = rois[n * 5 + 2];
    const float x2 = rois[n * 5 + 3];
    const float y2 = rois[n * 5 + 4];

    float w = x2 - x1; w = (w <= 0.f) ? 1e-14f : w;
    float h = y2 - y1; h = (h <= 0.f) ? 1e-14f : h;
    float kf = 4.f + log2f(sqrtf(w * h) * (1.f / 224.f));
    kf = fminf(fmaxf(kf, 2.f), 5.f);
    const float kr = rintf(kf);                 // round-half-even == jnp.round
    const int   lvl = (int)kr - 2;              // 0..3
    const float scale = exp2f(kr);
    const int   HW = 256 >> lvl;

    const int t = threadIdx.x;

    if (t < 2 * PRE) {
        const bool isx = t < PRE;
        const int  j = isx ? t : t - PRE;
        const float a1 = isx ? x1 : y1;
        const float a2 = isx ? x2 : y2;
        const float a1s = a1 / scale, a2s = a2 / scale;
        const float cen  = (a1s + a2s) * 0.5f;
        const float half = (a2s - a1s) * 0.5f;
        const float tt = -1.f + (2.f / 13.f) * (float)j;
        const float p  = cen + tt * half;
        const float p0 = floorf(p);
        const float d  = p - p0;
        const float HWf = (float)HW;
        const float m0 = (p0 >= 0.f && p0 < HWf) ? 1.f : 0.f;
        const float m1 = (p0 + 1.f >= 0.f && p0 + 1.f < HWf) ? 1.f : 0.f;
        const int c0i = min(max((int)p0, 0), HW - 1);
        const int c1i = min(max((int)p0 + 1, 0), HW - 1);
        if (isx) { sxw0[j] = (1.f - d) * m0; sxw1[j] = d * m1; sxc0[j] = c0i; sxc1[j] = c1i; }
        else     { syw0[j] = (1.f - d) * m0; syw1[j] = d * m1; syc0[j] = c0i; syc1[j] = c1i; }
    }
    __syncthreads();

    if (HWC) {
        for (int s = t; s < PRE * PRE; s += 256) {
            const int i = s / PRE;
            const int j = s - i * PRE;
            wtab[s] = make_float4(syw0[i] * sxw0[j], syw0[i] * sxw1[j],
                                  syw1[i] * sxw0[j], syw1[i] * sxw1[j]);
            otab[s] = make_int4((syc0[i] * HW + sxc0[j]) << 9, (syc0[i] * HW + sxc1[j]) << 9,
                                (syc1[i] * HW + sxc0[j]) << 9, (syc1[i] * HW + sxc1[j]) << 9);
        }
        __syncthreads();
    }

    const int g     = t & 15;                   // ch-group (16 x 4ch = 64 ch)
    const int ph    = t >> 4;                   // 0..15 pixel phase
    const int cbase = ch0 + (g << 2);

    if (HWC) {
        const unsigned int off = (lvl == 0) ? OFF_P2 : (lvl == 1) ? OFF_P3 : (lvl == 2) ? OFF_P4 : OFF_P5;
        const char* __restrict__ base = (const char*)(ws + off);
        const int cb2 = cbase << 1;

        // per-pixel body (inlined; loads across the unrolled calls get scheduled together)
        #define DO_PIXEL(P)                                                           \
        {                                                                             \
            const int p_ = (P);                                                       \
            const int oy_ = p_ / 7;                                                   \
            const int ox_ = p_ - oy_ * 7;                                             \
            const int s00 = oy_ * 28 + (ox_ << 1);                                    \
            const int4  oA = otab[s00];      const float4 wA = wtab[s00];             \
            const int4  oB = otab[s00 + 1];  const float4 wB = wtab[s00 + 1];         \
            const int4  oC = otab[s00 + 14]; const float4 wC = wtab[s00 + 14];        \
            const int4  oD = otab[s00 + 15]; const float4 wD = wtab[s00 + 15];        \
            const uint2 A00 = *(const uint2*)(base + (oA.x + cb2));                   \
            const uint2 A01 = *(const uint2*)(base + (oA.y + cb2));                   \
            const uint2 A10 = *(const uint2*)(base + (oA.z + cb2));                   \
            const uint2 A11 = *(const uint2*)(base + (oA.w + cb2));                   \
            const uint2 B00 = *(const uint2*)(base + (oB.x + cb2));                   \
            const uint2 B01 = *(const uint2*)(base + (oB.y + cb2));                   \
            const uint2 B10 = *(const uint2*)(base + (oB.z + cb2));                   \
            const uint2 B11 = *(const uint2*)(base + (oB.w + cb2));                   \
            const uint2 C00 = *(const uint2*)(base + (oC.x + cb2));                   \
            const uint2 C01 = *(const uint2*)(base + (oC.y + cb2));                   \
            const uint2 C10 = *(const uint2*)(base + (oC.z + cb2));                   \
            const uint2 C11 = *(const uint2*)(base + (oC.w + cb2));                   \
            const uint2 D00 = *(const uint2*)(base + (oD.x + cb2));                   \
            const uint2 D01 = *(const uint2*)(base + (oD.y + cb2));                   \
            const uint2 D10 = *(const uint2*)(base + (oD.z + cb2));                   \
            const uint2 D11 = *(const uint2*)(base + (oD.w + cb2));                   \
            const float4 vA = bilerp4(A00, A01, A10, A11, wA);                        \
            const float4 vB = bilerp4(B00, B01, B10, B11, wB);                        \
            const float4 vC = bilerp4(C00, C01, C10, C11, wC);                        \
            const float4 vD = bilerp4(D00, D01, D10, D11, wD);                        \
            float4 m_;                                                               \
            m_.x = fmaxf(fmaxf(vA.x, vB.x), fmaxf(vC.x, vD.x));                       \
            m_.y = fmaxf(fmaxf(vA.y, vB.y), fmaxf(vC.y, vD.y));                       \
            m_.z = fmaxf(fmaxf(vA.z, vB.z), fmaxf(vC.z, vD.z));                       \
            m_.w = fmaxf(fmaxf(vA.w, vB.w), fmaxf(vC.w, vD.w));                       \
            *(float4*)&sout[p_ * SROW + (g << 2)] = m_;                               \
        }

        DO_PIXEL(ph)
        DO_PIXEL(ph + 16)
        DO_PIXEL(ph + 32)
        if (ph == 0) DO_PIXEL(48)
        #undef DO_PIXEL
    } else {
        const float* __restrict__ fbF = (lvl == 0) ? p2 : (lvl == 1) ? p3 : (lvl == 2) ? p4 : p5;
        const int HW2 = HW * HW;
        for (int p = ph; p < PIX; p += 16) {
            const int oy = p / 7;
            const int ox = p - oy * 7;
            float4 m = make_float4(-3.4e38f, -3.4e38f, -3.4e38f, -3.4e38f);
            #pragma unroll
            for (int sy = 0; sy < 2; ++sy) {
                const int i = oy * 2 + sy;
                const float wy0 = syw0[i], wy1 = syw1[i];
                const int   yc0 = syc0[i], yc1 = syc1[i];
                #pragma unroll
                for (int sx = 0; sx < 2; ++sx) {
                    const int j = ox * 2 + sx;
                    const float w00 = wy0 * sxw0[j], w01 = wy0 * sxw1[j];
                    const float w10 = wy1 * sxw0[j], w11 = wy1 * sxw1[j];
                    const int   xc0 = sxc0[j], xc1 = sxc1[j];
                    float vv[4];
                    #pragma unroll
                    for (int k = 0; k < 4; ++k) {
                        const size_t cb = (size_t)(cbase + k) * HW2;
                        const float a00 = fbF[cb + yc0 * HW + xc0];
                        const float a01 = fbF[cb + yc0 * HW + xc1];
                        const float a10 = fbF[cb + yc1 * HW + xc0];
                        const float a11 = fbF[cb + yc1 * HW + xc1];
                        vv[k] = fmaf(a00, w00, fmaf(a01, w01, fmaf(a10, w10, a11 * w11)));
                    }
                    m.x = fmaxf(m.x, vv[0]);
                    m.y = fmaxf(m.y, vv[1]);
                    m.z = fmaxf(m.z, vv[2]);
                    m.w = fmaxf(m.w, vv[3]);
                }
            }
            *(float4*)&sout[p * SROW + (g << 2)] = m;
        }
    }
    __syncthreads();

    // coalesced NCHW write of this 64-channel quarter (cached stores)
    const size_t ob = (size_t)n * OUT_PER_ROI + (size_t)ch0 * PIX;
    for (int o = t; o < QTR_OUT; o += 256) {
        const int c  = o / PIX;
        const int pp = o - c * PIX;
        out[ob + o] = sout[pp * SROW + c];
    }
}

extern "C" void kernel_launch(void* const* d_in, const int* in_sizes, int n_in,
                              void* d_out, int out_size, void* d_ws, size_t ws_size,
                              hipStream_t stream) {
    const float* p2   = (const float*)d_in[0];
    const float* p3   = (const float*)d_in[1];
    const float* p4   = (const float*)d_in[2];
    const float* p5   = (const float*)d_in[3];
    const float* rois = (const float*)d_in[4];
    float* out = (float*)d_out;
    const int N = in_sizes[4] / 5;

    const size_t need = (size_t)WS_ELEMS * sizeof(unsigned short);
    if (ws_size >= need) {
        unsigned short* ws = (unsigned short*)d_ws;
        transpose_all_k<<<680, 256, 0, stream>>>(p2, p3, p4, p5, ws);
        roi_align_k<true><<<dim3(N, 4), 256, 0, stream>>>(p2, p3, p4, p5, ws, rois, out);
    } else {
        roi_align_k<false><<<dim3(N, 4), 256, 0, stream>>>(p2, p3, p4, p5, nullptr, rois, out);
    }
}